// Round 17
// baseline (54.043 us; speedup 1.0000x reference)
//
#include <hip/hip_runtime.h>

// GPLoss: gradient-profile loss, scalar output.
// R16 structure + (a) 4-step partial DPP row reduction with packed rowbuf
// writes, (b) fused finisher kernel (col reduce + atomic-ticket final).
// Main: 768 blocks x 512 thr; block = one 64-row band (8 waves = 4 rowgrps
// x 2 colhalves); wave = 16 rows x 256 cols; lane owns 4 cols (float4 loads,
// scalar halo); packed fp32 math (v_pk_fma_f32). colPart 768 slots = 9.4 MB
// (L3-safe). ws: colPart f32[768][6][512] ; rowPart f32[768][2] ;
// dblk f64[192] ; ticket u32.

typedef float f32x4 __attribute__((ext_vector_type(4)));
typedef float f32x2 __attribute__((ext_vector_type(2)));

__device__ __forceinline__ f32x2 fma2(f32x2 a, f32x2 b, f32x2 c){
  return __builtin_elementwise_fma(a, b, c);
}

#define DPP_ADD(x, ctrl, rmask) \
  x += __int_as_float(__builtin_amdgcn_update_dpp(0, __float_as_int(x), ctrl, rmask, 0xf, false))

__device__ __forceinline__ float dpp_psum16(float x){  // 16-lane partial
  DPP_ADD(x, 0x111, 0xf);   // row_shr:1
  DPP_ADD(x, 0x112, 0xf);   // row_shr:2
  DPP_ADD(x, 0x114, 0xf);   // row_shr:4
  DPP_ADD(x, 0x118, 0xf);   // row_shr:8
  return x;                 // lanes 15/31/47/63 hold their 16-lane sums
}

__device__ __forceinline__ float wave_dpp_sum(float x){
  DPP_ADD(x, 0x111, 0xf);
  DPP_ADD(x, 0x112, 0xf);
  DPP_ADD(x, 0x114, 0xf);
  DPP_ADD(x, 0x118, 0xf);
  DPP_ADD(x, 0x142, 0xa);   // row_bcast:15 -> rows 1,3
  DPP_ADD(x, 0x143, 0xc);   // row_bcast:31 -> rows 2,3
  return x;                 // lane 63 holds the 64-lane sum
}

__device__ __forceinline__ float cos_sim(float d, float sx, float sr){
  float nx = fmaxf(sqrtf(sx), 1e-12f);
  float nr = fmaxf(sqrtf(sr), 1e-12f);
  return d / (nx * nr);
}

__global__ __launch_bounds__(512) void gp_uni(
    const float* __restrict__ X, const float* __restrict__ R,
    float* __restrict__ rowPart, float* __restrict__ colPart)
{
  const int bid = blockIdx.x;
  const int p = bid >> 3, q = bid & 7;         // plane, 64-row band
  const int tid = threadIdx.x, w = tid >> 6, l = tid & 63;
  const int rg = w >> 1;                        // row-group 0..3
  const int wp = w & 1;                         // col half: wp*256
  const size_t plane = (size_t)p * (512u * 512u);
  const float* xp = X + plane;
  const float* rp = R + plane;
  const int c  = wp*256 + 4*l;                  // cols c..c+3
  const int cn = (c+4 < 512) ? c+4 : 511;       // f_v halo col (clamped)
  const bool tlast = (c == 508);                // col 511: no f_v
  const int h0 = q*64 + rg*16;                  // first row of this wave

  __shared__ float Abuf[6][512];                // 12 KB (rowgrps 0,2)
  __shared__ float Bbuf[6][512];                // 12 KB (rowgrps 1,3)
  __shared__ float rowbuf[64][2][4][8];         // 16 KB: 8 partials x 6 stats

  f32x2 cv0a={0.f,0.f}, cv0b={0.f,0.f}, cv1a={0.f,0.f}, cv1b={0.f,0.f};
  f32x2 cv2a={0.f,0.f}, cv2b={0.f,0.f}, ch0a={0.f,0.f}, ch0b={0.f,0.f};
  f32x2 ch1a={0.f,0.f}, ch1b={0.f,0.f}, ch2a={0.f,0.f}, ch2b={0.f,0.f};

  const float* xr0 = xp + (size_t)h0*512;
  const float* rr0 = rp + (size_t)h0*512;
  float4 xc4 = *(const float4*)(xr0 + c);
  float4 rc4 = *(const float4*)(rr0 + c);
  float  xhv = xr0[cn], rhv = rr0[cn];

  #pragma unroll 2
  for (int k = 0; k < 16; ++k){
    const int h  = h0 + k;
    const int hn = (h+1 < 512) ? h+1 : 511;     // h==511: next==cur -> dh=0
    const float* xr = xp + (size_t)hn*512;
    const float* rr = rp + (size_t)hn*512;
    const float4 nx4 = *(const float4*)(xr + c);
    const float4 nr4 = *(const float4*)(rr + c);
    const float  nxh = xr[cn], nrh = rr[cn];

    const f32x2 ax01 = {xc4.x, xc4.y}, ax23 = {xc4.z, xc4.w};
    const f32x2 ar01 = {rc4.x, rc4.y}, ar23 = {rc4.z, rc4.w};
    const f32x2 bx01 = {nx4.x, nx4.y}, bx23 = {nx4.z, nx4.w};
    const f32x2 br01 = {nr4.x, nr4.y}, br23 = {nr4.z, nr4.w};
    const f32x2 sx01 = {xc4.y, xc4.z}, sx23 = {xc4.w, tlast ? xc4.w : xhv};
    const f32x2 sr01 = {rc4.y, rc4.z}, sr23 = {rc4.w, tlast ? rc4.w : rhv};

    const f32x2 dv01 = ax01 - sx01, dv23 = ax23 - sx23;   // dv3=0 when tlast
    const f32x2 ev01 = ar01 - sr01, ev23 = ar23 - sr23;
    const f32x2 dh01 = ax01 - bx01, dh23 = ax23 - bx23;
    const f32x2 eh01 = ar01 - br01, eh23 = ar23 - br23;

    f32x2 p0v = dv01*ev01; p0v = fma2(dv23, ev23, p0v);
    f32x2 p1v = dv01*dv01; p1v = fma2(dv23, dv23, p1v);
    f32x2 p2v = ev01*ev01; p2v = fma2(ev23, ev23, p2v);
    f32x2 q0v = dh01*eh01; q0v = fma2(dh23, eh23, q0v);
    f32x2 q1v = dh01*dh01; q1v = fma2(dh23, dh23, q1v);
    f32x2 q2v = eh01*eh01; q2v = fma2(eh23, eh23, q2v);

    cv0a = fma2(dv01, ev01, cv0a); cv0b = fma2(dv23, ev23, cv0b);
    cv1a = fma2(dv01, dv01, cv1a); cv1b = fma2(dv23, dv23, cv1b);
    cv2a = fma2(ev01, ev01, cv2a); cv2b = fma2(ev23, ev23, cv2b);
    ch0a = fma2(dh01, eh01, ch0a); ch0b = fma2(dh23, eh23, ch0b);
    ch1a = fma2(dh01, dh01, ch1a); ch1b = fma2(dh23, dh23, ch1b);
    ch2a = fma2(eh01, eh01, ch2a); ch2b = fma2(eh23, eh23, ch2b);

    float p0 = p0v.x + p0v.y, p1 = p1v.x + p1v.y, p2 = p2v.x + p2v.y;
    float q0 = q0v.x + q0v.y, q1 = q1v.x + q1v.y, q2 = q2v.x + q2v.y;

    // 6 chains x 4-step partial DPP; lanes 15/31/47/63 write packed partials
    p0 = dpp_psum16(p0); p1 = dpp_psum16(p1); p2 = dpp_psum16(p2);
    q0 = dpp_psum16(q0); q1 = dpp_psum16(q1); q2 = dpp_psum16(q2);
    if ((l & 15) == 15){
      float* dst = &rowbuf[rg*16 + k][wp][l >> 4][0];
      *(float4*)dst       = make_float4(p0, p1, p2, q0);
      *(float2*)(dst + 4) = make_float2(q1, q2);
    }

    xc4 = nx4; rc4 = nr4; xhv = nxh; rhv = nrh;
  }

  // ---- col merge tree: rg0->A, rg1->B ; rg2+=A, rg3+=B ; store A+B
  if (rg == 0){
    *(float4*)&Abuf[0][c] = make_float4(cv0a.x,cv0a.y,cv0b.x,cv0b.y);
    *(float4*)&Abuf[1][c] = make_float4(cv1a.x,cv1a.y,cv1b.x,cv1b.y);
    *(float4*)&Abuf[2][c] = make_float4(cv2a.x,cv2a.y,cv2b.x,cv2b.y);
    *(float4*)&Abuf[3][c] = make_float4(ch0a.x,ch0a.y,ch0b.x,ch0b.y);
    *(float4*)&Abuf[4][c] = make_float4(ch1a.x,ch1a.y,ch1b.x,ch1b.y);
    *(float4*)&Abuf[5][c] = make_float4(ch2a.x,ch2a.y,ch2b.x,ch2b.y);
  } else if (rg == 1){
    *(float4*)&Bbuf[0][c] = make_float4(cv0a.x,cv0a.y,cv0b.x,cv0b.y);
    *(float4*)&Bbuf[1][c] = make_float4(cv1a.x,cv1a.y,cv1b.x,cv1b.y);
    *(float4*)&Bbuf[2][c] = make_float4(cv2a.x,cv2a.y,cv2b.x,cv2b.y);
    *(float4*)&Bbuf[3][c] = make_float4(ch0a.x,ch0a.y,ch0b.x,ch0b.y);
    *(float4*)&Bbuf[4][c] = make_float4(ch1a.x,ch1a.y,ch1b.x,ch1b.y);
    *(float4*)&Bbuf[5][c] = make_float4(ch2a.x,ch2a.y,ch2b.x,ch2b.y);
  }
  __syncthreads();
  if (rg == 2 || rg == 3){
    float (*buf)[512] = (rg == 2) ? Abuf : Bbuf;
    float4 t;
    t = *(float4*)&buf[0][c]; t.x+=cv0a.x; t.y+=cv0a.y; t.z+=cv0b.x; t.w+=cv0b.y; *(float4*)&buf[0][c]=t;
    t = *(float4*)&buf[1][c]; t.x+=cv1a.x; t.y+=cv1a.y; t.z+=cv1b.x; t.w+=cv1b.y; *(float4*)&buf[1][c]=t;
    t = *(float4*)&buf[2][c]; t.x+=cv2a.x; t.y+=cv2a.y; t.z+=cv2b.x; t.w+=cv2b.y; *(float4*)&buf[2][c]=t;
    t = *(float4*)&buf[3][c]; t.x+=ch0a.x; t.y+=ch0a.y; t.z+=ch0b.x; t.w+=ch0b.y; *(float4*)&buf[3][c]=t;
    t = *(float4*)&buf[4][c]; t.x+=ch1a.x; t.y+=ch1a.y; t.z+=ch1b.x; t.w+=ch1b.y; *(float4*)&buf[4][c]=t;
    t = *(float4*)&buf[5][c]; t.x+=ch2a.x; t.y+=ch2a.y; t.z+=ch2b.x; t.w+=ch2b.y; *(float4*)&buf[5][c]=t;
  }
  __syncthreads();
  {
    const f32x4* A4 = (const f32x4*)Abuf;
    const f32x4* B4 = (const f32x4*)Bbuf;
    f32x4* s4 = (f32x4*)(colPart + (size_t)bid * (6*512));
    for (int idx = tid; idx < 768; idx += 512)
      s4[idx] = A4[idx] + B4[idx];
  }

  // ---- row finalize: wave 0, thread tid handles row tid (8 packed partials)
  if (tid < 64){
    float a0=0.f,a1=0.f,a2=0.f,b0=0.f,b1=0.f,b2=0.f;
    #pragma unroll
    for (int wp_ = 0; wp_ < 2; ++wp_){
      #pragma unroll
      for (int g = 0; g < 4; ++g){
        const float* src = &rowbuf[tid][wp_][g][0];
        const float4 sA = *(const float4*)src;
        const float2 sB = *(const float2*)(src + 4);
        a0 += sA.x; a1 += sA.y; a2 += sA.z;
        b0 += sA.w; b1 += sB.x; b2 += sB.y;
      }
    }
    float rv = cos_sim(a0,a1,a2);
    const int h = q*64 + tid;
    float rh = (h < 511) ? cos_sim(b0,b1,b2) : 0.f;
    rv = wave_dpp_sum(rv);
    rh = wave_dpp_sum(rh);
    if (tid == 63){
      rowPart[2*bid+0] = rv;
      rowPart[2*bid+1] = rh;
    }
  }
}

// ---------------- fused finisher: col reduce + last-block final --------------
__global__ __launch_bounds__(256) void gp_fin2(
    const float* __restrict__ colPart, const float* __restrict__ rowPart,
    double* __restrict__ dblk, unsigned int* __restrict__ ticket,
    float* __restrict__ out)
{
  const int bid = blockIdx.x;      // 0..191
  const int p = bid >> 1;
  const int f = bid & 1;           // 0 = fv, 1 = fh
  const int tid = threadIdx.x;
  const int w = tid >> 6, l = tid & 63;

  double acc = 0.0;
  for (int c = tid; c < 512; c += 256){
    float d = 0.f, a = 0.f, b = 0.f;
    #pragma unroll
    for (int s = 0; s < 8; ++s){
      const float* sp = colPart + ((size_t)(p*8 + s) * 6 + f*3) * 512;
      d += sp[c]; a += sp[512 + c]; b += sp[1024 + c];
    }
    acc += (double)cos_sim(d, a, b);   // fv col 511: cos(0,0,0)=0, harmless
  }
  #pragma unroll
  for (int m = 1; m < 64; m <<= 1) acc += __shfl_xor(acc, m, 64);
  __shared__ double ls[4];
  if (l == 0) ls[w] = acc;
  __syncthreads();

  __shared__ unsigned int my;
  if (tid == 0){
    const double total = ls[0] + ls[1] + ls[2] + ls[3];
    atomicExch((unsigned long long*)&dblk[bid],
               (unsigned long long)__double_as_longlong(total));
    __threadfence();
    my = atomicAdd(ticket, 1u);
  }
  __syncthreads();

  if (my == 191){                    // last block: final combine
    double rv = 0, rh = 0, cv = 0, ch = 0;
    for (int i = tid; i < 768; i += 256){
      rv += (double)rowPart[2*i];
      rh += (double)rowPart[2*i+1];
    }
    for (int i = tid; i < 192; i += 256){
      const unsigned long long u =
        atomicAdd((unsigned long long*)&dblk[i], 0ull);  // coherent read
      const double v = __longlong_as_double((long long)u);
      if (i & 1) ch += v; else cv += v;
    }
    #pragma unroll
    for (int m = 1; m < 64; m <<= 1){
      rv += __shfl_xor(rv, m, 64); rh += __shfl_xor(rh, m, 64);
      cv += __shfl_xor(cv, m, 64); ch += __shfl_xor(ch, m, 64);
    }
    __shared__ double fs[4][4];
    if (l == 0){ fs[w][0]=rv; fs[w][1]=rh; fs[w][2]=cv; fs[w][3]=ch; }
    __syncthreads();
    if (tid == 0){
      double RV=0, RH=0, CV=0, CH=0;
      #pragma unroll
      for (int i = 0; i < 4; ++i){ RV+=fs[i][0]; RH+=fs[i][1]; CV+=fs[i][2]; CH+=fs[i][3]; }
      const double t = RV/512.0 + RH/511.0 + CV/511.0 + CH/512.0;
      out[0] = (float)(-t / 32.0);
    }
  }
}

extern "C" void kernel_launch(void* const* d_in, const int* in_sizes, int n_in,
                              void* d_out, int out_size, void* d_ws, size_t ws_size,
                              hipStream_t stream) {
  const float* X = (const float*)d_in[0];
  const float* R = (const float*)d_in[1];
  float* out = (float*)d_out;

  float*  colPart = (float*)d_ws;                          // 768*6*512 f32
  float*  rowPart = colPart + (size_t)768*6*512;           // 768*2 f32
  double* dblk    = (double*)(rowPart + (size_t)768*2);    // 192 f64
  unsigned int* ticket = (unsigned int*)(dblk + 192);      // 1 u32

  hipMemsetAsync(ticket, 0, 4, stream);
  gp_uni <<<dim3(768), dim3(512), 0, stream>>>(X, R, rowPart, colPart);
  gp_fin2<<<dim3(192), dim3(256), 0, stream>>>(colPart, rowPart, dblk, ticket, out);
}

// Round 18
// 46.925 us; speedup vs baseline: 1.1517x; 1.1517x over previous
//
#include <hip/hip_runtime.h>

// GPLoss: gradient-profile loss, scalar output.
// R16 structure (best: 47.4 us) + packed lane-63 rowbuf writes (b128+b64,
// single active lane -> conflict-free; -4 LDS issue slots per wave-row).
// Main: 768 blocks x 512 thr; block = one 64-row band (8 waves = 4 rowgrps
// x 2 colhalves); wave = 16 rows x 256 cols; lane owns 4 cols (float4 loads,
// scalar halo); packed fp32 math (v_pk_fma_f32); 6-step full-wave DPP row
// reduction (VALU pipe only). colPart 768 slots = 9.4 MB (L3-safe).
// ws: colPart f32[768][6][512] ; rowPart f32[768][2] ; dblk f64[192]

typedef float f32x4 __attribute__((ext_vector_type(4)));
typedef float f32x2 __attribute__((ext_vector_type(2)));

__device__ __forceinline__ f32x2 fma2(f32x2 a, f32x2 b, f32x2 c){
  return __builtin_elementwise_fma(a, b, c);
}

#define DPP_ADD(x, ctrl, rmask) \
  x += __int_as_float(__builtin_amdgcn_update_dpp(0, __float_as_int(x), ctrl, rmask, 0xf, false))

__device__ __forceinline__ float wave_dpp_sum(float x){
  DPP_ADD(x, 0x111, 0xf);   // row_shr:1
  DPP_ADD(x, 0x112, 0xf);   // row_shr:2
  DPP_ADD(x, 0x114, 0xf);   // row_shr:4
  DPP_ADD(x, 0x118, 0xf);   // row_shr:8
  DPP_ADD(x, 0x142, 0xa);   // row_bcast:15 -> rows 1,3
  DPP_ADD(x, 0x143, 0xc);   // row_bcast:31 -> rows 2,3
  return x;                 // lane 63 holds the 64-lane sum
}

__device__ __forceinline__ float cos_sim(float d, float sx, float sr){
  float nx = fmaxf(sqrtf(sx), 1e-12f);
  float nr = fmaxf(sqrtf(sr), 1e-12f);
  return d / (nx * nr);
}

__global__ __launch_bounds__(512) void gp_uni(
    const float* __restrict__ X, const float* __restrict__ R,
    float* __restrict__ rowPart, float* __restrict__ colPart)
{
  const int bid = blockIdx.x;
  const int p = bid >> 3, q = bid & 7;         // plane, 64-row band
  const int tid = threadIdx.x, w = tid >> 6, l = tid & 63;
  const int rg = w >> 1;                        // row-group 0..3
  const int wp = w & 1;                         // col half: wp*256
  const size_t plane = (size_t)p * (512u * 512u);
  const float* xp = X + plane;
  const float* rp = R + plane;
  const int c  = wp*256 + 4*l;                  // cols c..c+3
  const int cn = (c+4 < 512) ? c+4 : 511;       // f_v halo col (clamped)
  const bool tlast = (c == 508);                // col 511: no f_v
  const int h0 = q*64 + rg*16;                  // first row of this wave

  __shared__ float Abuf[6][512];                // 12 KB (rowgrps 0,2)
  __shared__ float Bbuf[6][512];                // 12 KB (rowgrps 1,3)
  __shared__ float rowbuf[64][2][8];            // 4 KB, 16B-aligned entries

  f32x2 cv0a={0.f,0.f}, cv0b={0.f,0.f}, cv1a={0.f,0.f}, cv1b={0.f,0.f};
  f32x2 cv2a={0.f,0.f}, cv2b={0.f,0.f}, ch0a={0.f,0.f}, ch0b={0.f,0.f};
  f32x2 ch1a={0.f,0.f}, ch1b={0.f,0.f}, ch2a={0.f,0.f}, ch2b={0.f,0.f};

  const float* xr0 = xp + (size_t)h0*512;
  const float* rr0 = rp + (size_t)h0*512;
  float4 xc4 = *(const float4*)(xr0 + c);
  float4 rc4 = *(const float4*)(rr0 + c);
  float  xhv = xr0[cn], rhv = rr0[cn];

  #pragma unroll 2
  for (int k = 0; k < 16; ++k){
    const int h  = h0 + k;
    const int hn = (h+1 < 512) ? h+1 : 511;     // h==511: next==cur -> dh=0
    const float* xr = xp + (size_t)hn*512;
    const float* rr = rp + (size_t)hn*512;
    const float4 nx4 = *(const float4*)(xr + c);
    const float4 nr4 = *(const float4*)(rr + c);
    const float  nxh = xr[cn], nrh = rr[cn];

    const f32x2 ax01 = {xc4.x, xc4.y}, ax23 = {xc4.z, xc4.w};
    const f32x2 ar01 = {rc4.x, rc4.y}, ar23 = {rc4.z, rc4.w};
    const f32x2 bx01 = {nx4.x, nx4.y}, bx23 = {nx4.z, nx4.w};
    const f32x2 br01 = {nr4.x, nr4.y}, br23 = {nr4.z, nr4.w};
    const f32x2 sx01 = {xc4.y, xc4.z}, sx23 = {xc4.w, tlast ? xc4.w : xhv};
    const f32x2 sr01 = {rc4.y, rc4.z}, sr23 = {rc4.w, tlast ? rc4.w : rhv};

    const f32x2 dv01 = ax01 - sx01, dv23 = ax23 - sx23;   // dv3=0 when tlast
    const f32x2 ev01 = ar01 - sr01, ev23 = ar23 - sr23;
    const f32x2 dh01 = ax01 - bx01, dh23 = ax23 - bx23;
    const f32x2 eh01 = ar01 - br01, eh23 = ar23 - br23;

    f32x2 p0v = dv01*ev01; p0v = fma2(dv23, ev23, p0v);
    f32x2 p1v = dv01*dv01; p1v = fma2(dv23, dv23, p1v);
    f32x2 p2v = ev01*ev01; p2v = fma2(ev23, ev23, p2v);
    f32x2 q0v = dh01*eh01; q0v = fma2(dh23, eh23, q0v);
    f32x2 q1v = dh01*dh01; q1v = fma2(dh23, dh23, q1v);
    f32x2 q2v = eh01*eh01; q2v = fma2(eh23, eh23, q2v);

    cv0a = fma2(dv01, ev01, cv0a); cv0b = fma2(dv23, ev23, cv0b);
    cv1a = fma2(dv01, dv01, cv1a); cv1b = fma2(dv23, dv23, cv1b);
    cv2a = fma2(ev01, ev01, cv2a); cv2b = fma2(ev23, ev23, cv2b);
    ch0a = fma2(dh01, eh01, ch0a); ch0b = fma2(dh23, eh23, ch0b);
    ch1a = fma2(dh01, dh01, ch1a); ch1b = fma2(dh23, dh23, ch1b);
    ch2a = fma2(eh01, eh01, ch2a); ch2b = fma2(eh23, eh23, ch2b);

    float p0 = p0v.x + p0v.y, p1 = p1v.x + p1v.y, p2 = p2v.x + p2v.y;
    float q0 = q0v.x + q0v.y, q1 = q1v.x + q1v.y, q2 = q2v.x + q2v.y;

    // 6 independent DPP chains (VALU pipe)
    p0 = wave_dpp_sum(p0); p1 = wave_dpp_sum(p1); p2 = wave_dpp_sum(p2);
    q0 = wave_dpp_sum(q0); q1 = wave_dpp_sum(q1); q2 = wave_dpp_sum(q2);
    if (l == 63){                       // single active lane: conflict-free
      float* dst = &rowbuf[rg*16 + k][wp][0];
      *(float4*)dst       = make_float4(p0, p1, p2, q0);
      *(float2*)(dst + 4) = make_float2(q1, q2);
    }

    xc4 = nx4; rc4 = nr4; xhv = nxh; rhv = nrh;
  }

  // ---- col merge tree: rg0->A, rg1->B ; rg2+=A, rg3+=B ; store A+B
  if (rg == 0){
    *(float4*)&Abuf[0][c] = make_float4(cv0a.x,cv0a.y,cv0b.x,cv0b.y);
    *(float4*)&Abuf[1][c] = make_float4(cv1a.x,cv1a.y,cv1b.x,cv1b.y);
    *(float4*)&Abuf[2][c] = make_float4(cv2a.x,cv2a.y,cv2b.x,cv2b.y);
    *(float4*)&Abuf[3][c] = make_float4(ch0a.x,ch0a.y,ch0b.x,ch0b.y);
    *(float4*)&Abuf[4][c] = make_float4(ch1a.x,ch1a.y,ch1b.x,ch1b.y);
    *(float4*)&Abuf[5][c] = make_float4(ch2a.x,ch2a.y,ch2b.x,ch2b.y);
  } else if (rg == 1){
    *(float4*)&Bbuf[0][c] = make_float4(cv0a.x,cv0a.y,cv0b.x,cv0b.y);
    *(float4*)&Bbuf[1][c] = make_float4(cv1a.x,cv1a.y,cv1b.x,cv1b.y);
    *(float4*)&Bbuf[2][c] = make_float4(cv2a.x,cv2a.y,cv2b.x,cv2b.y);
    *(float4*)&Bbuf[3][c] = make_float4(ch0a.x,ch0a.y,ch0b.x,ch0b.y);
    *(float4*)&Bbuf[4][c] = make_float4(ch1a.x,ch1a.y,ch1b.x,ch1b.y);
    *(float4*)&Bbuf[5][c] = make_float4(ch2a.x,ch2a.y,ch2b.x,ch2b.y);
  }
  __syncthreads();
  if (rg == 2 || rg == 3){
    float (*buf)[512] = (rg == 2) ? Abuf : Bbuf;
    float4 t;
    t = *(float4*)&buf[0][c]; t.x+=cv0a.x; t.y+=cv0a.y; t.z+=cv0b.x; t.w+=cv0b.y; *(float4*)&buf[0][c]=t;
    t = *(float4*)&buf[1][c]; t.x+=cv1a.x; t.y+=cv1a.y; t.z+=cv1b.x; t.w+=cv1b.y; *(float4*)&buf[1][c]=t;
    t = *(float4*)&buf[2][c]; t.x+=cv2a.x; t.y+=cv2a.y; t.z+=cv2b.x; t.w+=cv2b.y; *(float4*)&buf[2][c]=t;
    t = *(float4*)&buf[3][c]; t.x+=ch0a.x; t.y+=ch0a.y; t.z+=ch0b.x; t.w+=ch0b.y; *(float4*)&buf[3][c]=t;
    t = *(float4*)&buf[4][c]; t.x+=ch1a.x; t.y+=ch1a.y; t.z+=ch1b.x; t.w+=ch1b.y; *(float4*)&buf[4][c]=t;
    t = *(float4*)&buf[5][c]; t.x+=ch2a.x; t.y+=ch2a.y; t.z+=ch2b.x; t.w+=ch2b.y; *(float4*)&buf[5][c]=t;
  }
  __syncthreads();
  {
    const f32x4* A4 = (const f32x4*)Abuf;
    const f32x4* B4 = (const f32x4*)Bbuf;
    f32x4* s4 = (f32x4*)(colPart + (size_t)bid * (6*512));
    for (int idx = tid; idx < 768; idx += 512)
      s4[idx] = A4[idx] + B4[idx];
  }

  // ---- row finalize: wave 0, thread tid handles row tid
  if (tid < 64){
    const float4 sA0 = *(const float4*)&rowbuf[tid][0][0];
    const float2 sB0 = *(const float2*)&rowbuf[tid][0][4];
    const float4 sA1 = *(const float4*)&rowbuf[tid][1][0];
    const float2 sB1 = *(const float2*)&rowbuf[tid][1][4];
    const float a0 = sA0.x + sA1.x;
    const float a1 = sA0.y + sA1.y;
    const float a2 = sA0.z + sA1.z;
    const float b0 = sA0.w + sA1.w;
    const float b1 = sB0.x + sB1.x;
    const float b2 = sB0.y + sB1.y;
    float rv = cos_sim(a0,a1,a2);
    const int h = q*64 + tid;
    float rh = (h < 511) ? cos_sim(b0,b1,b2) : 0.f;
    rv = wave_dpp_sum(rv);
    rh = wave_dpp_sum(rh);
    if (tid == 63){
      rowPart[2*bid+0] = rv;
      rowPart[2*bid+1] = rh;
    }
  }
}

// ---------------- finish: reduce col partials over 8 slots -------------------
__global__ __launch_bounds__(256) void gp_cols(
    const float* __restrict__ colPart, double* __restrict__ dblk)
{
  const int p = blockIdx.x >> 1;
  const int f = blockIdx.x & 1;    // 0 = fv, 1 = fh
  const int tid = threadIdx.x;
  double acc = 0.0;
  for (int c = tid; c < 512; c += 256){
    float d = 0.f, a = 0.f, b = 0.f;
    #pragma unroll
    for (int s = 0; s < 8; ++s){
      const float* sp = colPart + ((size_t)(p*8 + s) * 6 + f*3) * 512;
      d += sp[c]; a += sp[512 + c]; b += sp[1024 + c];
    }
    acc += (double)cos_sim(d, a, b);   // fv col 511: cos(0,0,0)=0, harmless
  }
  #pragma unroll
  for (int m = 1; m < 64; m <<= 1) acc += __shfl_xor(acc, m, 64);
  __shared__ double ls[4];
  const int w = tid >> 6, l = tid & 63;
  if (l == 0) ls[w] = acc;
  __syncthreads();
  if (tid == 0) dblk[blockIdx.x] = ls[0] + ls[1] + ls[2] + ls[3];
}

__global__ __launch_bounds__(256) void gp_fin(
    const double* __restrict__ dblk, const float* __restrict__ rowPart,
    int nblk, float* __restrict__ out)
{
  const int tid = threadIdx.x;
  double rv = 0, rh = 0, cv = 0, ch = 0;
  for (int i = tid; i < nblk; i += 256){
    rv += (double)rowPart[2*i];
    rh += (double)rowPart[2*i+1];
  }
  for (int i = tid; i < 192; i += 256){
    if (i & 1) ch += dblk[i]; else cv += dblk[i];
  }
  #pragma unroll
  for (int m = 1; m < 64; m <<= 1){
    rv += __shfl_xor(rv, m, 64); rh += __shfl_xor(rh, m, 64);
    cv += __shfl_xor(cv, m, 64); ch += __shfl_xor(ch, m, 64);
  }
  __shared__ double ls[4][4];
  const int w = tid >> 6, l = tid & 63;
  if (l == 0){ ls[w][0]=rv; ls[w][1]=rh; ls[w][2]=cv; ls[w][3]=ch; }
  __syncthreads();
  if (tid == 0){
    double RV=0, RH=0, CV=0, CH=0;
    #pragma unroll
    for (int i = 0; i < 4; ++i){ RV+=ls[i][0]; RH+=ls[i][1]; CV+=ls[i][2]; CH+=ls[i][3]; }
    const double t = RV/512.0 + RH/511.0 + CV/511.0 + CH/512.0;
    out[0] = (float)(-t / 32.0);
  }
}

extern "C" void kernel_launch(void* const* d_in, const int* in_sizes, int n_in,
                              void* d_out, int out_size, void* d_ws, size_t ws_size,
                              hipStream_t stream) {
  const float* X = (const float*)d_in[0];
  const float* R = (const float*)d_in[1];
  float* out = (float*)d_out;

  float*  colPart = (float*)d_ws;                         // 768*6*512 f32
  float*  rowPart = colPart + (size_t)768*6*512;          // 768*2 f32
  double* dblk    = (double*)(rowPart + (size_t)768*2);   // 192 f64

  gp_uni <<<dim3(768), dim3(512), 0, stream>>>(X, R, rowPart, colPart);
  gp_cols<<<dim3(192), dim3(256), 0, stream>>>(colPart, dblk);
  gp_fin <<<dim3(1),   dim3(256), 0, stream>>>(dblk, rowPart, 768, out);
}